// Round 3
// baseline (391.651 us; speedup 1.0000x reference)
//
#include <hip/hip_runtime.h>
#include <hip/hip_fp16.h>
#include <stdint.h>

// Problem constants: B=4, S=128 -> M=512
#define M_DIM 512
#define K_DIM 4096
#define N_DIM 11008
#define KT (K_DIM / 64)        // 64 k-tiles of BK=64
#define NB_M 8                 // 64-row strips
#define NB_N 172               // 64-col strips
#define NBLK (NB_M * NB_N)     // 1376 two-wave blocks (split-K=2 inside the block)

typedef __attribute__((ext_vector_type(8))) _Float16 half8;
typedef __attribute__((ext_vector_type(4))) float floatx4;
typedef __attribute__((ext_vector_type(4))) int intx4;
typedef __attribute__((ext_vector_type(4))) unsigned int uintx4;

__device__ __forceinline__ unsigned int h2u(__half2 h) {
    union { __half2 h; unsigned int u; } c; c.h = h; return c.u;
}
__device__ __forceinline__ __half2 u2h(unsigned int u) {
    union { unsigned int u; __half2 h; } c; c.u = u; return c.h;
}
union U4H8 { uintx4 u; half8 h; };

// one packed dword (8 codes, pair-interleaved) -> b-operand half8 (R5-proven)
__device__ __forceinline__ half8 dequant8(unsigned int dw, __half2 s2, __half2 z2) {
    const __half2 kb = u2h(0x64006400u);   // (1024, 1024)
    U4H8 r;
    unsigned int p0 = (dw & 0x000F000Fu) | 0x64006400u;
    unsigned int p1 = ((dw >> 4)  & 0x000F000Fu) | 0x64006400u;
    unsigned int p2 = ((dw >> 8)  & 0x000F000Fu) | 0x64006400u;
    unsigned int p3 = ((dw >> 12) & 0x000F000Fu) | 0x64006400u;
    r.u.x = h2u(__hfma2(__hsub2(u2h(p0), kb), s2, z2));
    r.u.y = h2u(__hfma2(__hsub2(u2h(p1), kb), s2, z2));
    r.u.z = h2u(__hfma2(__hsub2(u2h(p2), kb), s2, z2));
    r.u.w = h2u(__hfma2(__hsub2(u2h(p3), kb), s2, z2));
    return r.h;
}

// ---------------------------------------------------------------------------
// Merged prep kernel.
// Blocks [0,1024): x fp32 [512,4096] -> f16 fragment-linear xb (R5-proven map).
// Blocks [1024,6528): wq int32 [N,K] -> packed nibbles. ONE BLOCK PER TILE now:
// thread t handles row r=t&127, k-half qh=t>>7 (octets qh*4..qh*4+3), reading
// 32 contiguous ints (one aligned 128 B line) and emitting 4 dwords. The store
// wpk[tile*1024 + (qh*4+c)*128 + r] is wave-contiguous in r -> every
// global_store_dword is a coalesced 256 B transaction (the old mapping
// scattered 64x4 B per store ~1 KB apart = ~16x the L2 write transactions
// for the same 22.5 MB).
// ---------------------------------------------------------------------------
__global__ __launch_bounds__(256) void prep_kernel(
        const float* __restrict__ x,  unsigned int* __restrict__ xb,
        const int*   __restrict__ wq, unsigned int* __restrict__ wpk) {
    int bx = blockIdx.x;
    if (bx < 1024) {
        int id = bx * 256 + threadIdx.x;        // chunk id, 262144 total
        int m  = id >> 9;
        int kc = id & 511;                      // k-octet within row
        const floatx4* src = (const floatx4*)(x + ((size_t)m << 12) + (kc << 3));
        floatx4 f0 = __builtin_nontemporal_load(src);
        floatx4 f1 = __builtin_nontemporal_load(src + 1);
        uintx4 v;
        v.x = h2u(__float22half2_rn(float2{f0.x, f0.y}));
        v.y = h2u(__float22half2_rn(float2{f0.z, f0.w}));
        v.z = h2u(__float22half2_rn(float2{f1.x, f1.y}));
        v.w = h2u(__float22half2_rn(float2{f1.z, f1.w}));
        int tm = m >> 7, r = m & 127, tk = kc >> 3, c = kc & 7;
        int igrp = r >> 4, rlow = r & 15, s01 = c >> 2, q = c & 3;
        int chunk = ((igrp * 2 + s01) << 6) + (q << 4) + rlow;
        size_t dstu = (((size_t)(tm * KT + tk)) << 12) + ((size_t)chunk << 2);
        *((uintx4*)(xb + dstu)) = v;
    } else {
        int tile = bx - 1024;                   // 0..5503 (86 nb x 64 kt)
        int t    = threadIdx.x;
        int r    = t & 127;                     // n-row within tile
        int qh   = t >> 7;                      // k-half: octets qh*4..qh*4+3
        int nb = tile >> 6, kt = tile & 63;
        const intx4* src = (const intx4*)(wq + (size_t)(nb * 128 + r) * K_DIM + kt * 64 + qh * 32);
        intx4 b[8];
#pragma unroll
        for (int u = 0; u < 8; ++u)
            b[u] = __builtin_nontemporal_load(src + u);
        size_t base = ((size_t)tile << 10) + (qh << 9) + r;
#pragma unroll
        for (int c = 0; c < 4; ++c) {
            intx4 lo = b[2 * c], hi = b[2 * c + 1];
            unsigned int u =
                (unsigned)lo.x | ((unsigned)lo.z << 4)  | ((unsigned)hi.x << 8)  | ((unsigned)hi.z << 12) |
                ((unsigned)lo.y << 16) | ((unsigned)lo.w << 20) | ((unsigned)hi.y << 24) | ((unsigned)hi.w << 28);
            wpk[base + (c << 7)] = u;           // lanes contiguous in r -> coalesced
        }
    }
}

// ---------------------------------------------------------------------------
// GEMM. Two waves per block, split-K=2 inside the block (R2 structure, proven
// correct). NEW: bijective XCD swizzle — 1376 blocks = 8 XCDs x 172 exactly.
// Raw blockIdx round-robins over XCDs, so bid=(bx&7)*172+(bx>>3) gives each
// XCD a contiguous band of bids: the 8 mbp blocks sharing one W 64-col strip
// (131 KB) now run on the SAME XCD ~concurrently -> W fetched once into that
// XCD's L2 and reused 8x (was: streamed 22.5 MB through every XCD's 4 MB L2).
// xb (4 MB) stays L2-resident per XCD.
// ---------------------------------------------------------------------------
__global__ __launch_bounds__(128, 3) void gemm_kernel(
        const unsigned int* __restrict__ xb,    // fragment-linear f16 x
        const unsigned int* __restrict__ wpk,   // packed nibbles, [q][r] tiles
        const float*        __restrict__ saz,   // [K/128, N, 2]
        float*              __restrict__ out)   // [M,N] fp32 (fully written here)
{
    const int bid  = (blockIdx.x & 7) * 172 + (blockIdx.x >> 3);   // XCD swizzle
    const int mbp  = bid & 7;                  // 64-row strip 0..7
    const int nbp  = bid >> 3;                 // 64-col strip 0..171
    const int lane = threadIdx.x & 63;
    const int wid  = threadIdx.x >> 6;         // split-K half 0/1
    const int q4   = lane >> 4;
    const int lr   = lane & 15;
    const int kt0  = wid * (KT / 2);
    const int kt1  = kt0 + (KT / 2);           // 32 k-tiles per wave

    const int tm    = mbp >> 1;                // xb 128-row tile
    const int igrp0 = (mbp & 1) * 4;           // first 16-row group
    const int nbt   = nbp >> 1;                // wpk 128-col tile
    const int wn    = (nbp & 1) * 64;

    // A fragments: 16 B units; frag (i, s01) at xat[i*128 + s01*64]
    const half8* xat = (const half8*)xb
        + (((size_t)(tm * KT + kt0)) << 10) + (igrp0 << 7) + lane;

    // W: frag (j, s01) at wbase[s01*512 + j*16]; advance 1024 dwords/k-tile
    const unsigned int* wbase =
        wpk + (((size_t)(nbt * KT + kt0)) << 10) + (q4 << 7) + wn + lr;

    const float2* saz2 = (const float2*)saz;
    const int nrow0 = nbp * 64 + lr;           // n-row for frag j: +j*16

    floatx4 acc[4][4];
    floatx4 zero4 = {0.f, 0.f, 0.f, 0.f};
#pragma unroll
    for (int i = 0; i < 4; ++i)
#pragma unroll
        for (int j = 0; j < 4; ++j)
            acc[i][j] = zero4;

    // prologue: W dwords for kt0
    unsigned int qw[8], qwn[8];
#pragma unroll
    for (int f = 0; f < 8; ++f)
        qw[f] = wbase[(f >> 2) * 512 + (f & 3) * 16];

    __half2 s2[4], z2[4];

    for (int kt = kt0; kt < kt1; ++kt) {
        // A loads for THIS iter (latency covered by scale/dequant VALU work)
        half8 av[8];
#pragma unroll
        for (int i = 0; i < 4; ++i) {
#pragma unroll
            for (int s = 0; s < 2; ++s)
                av[i * 2 + s] = xat[i * 128 + s * 64];
        }
        xat += 1024;

        // scales: new group every even kt (GS=128 = 2 k-tiles)
        if ((kt & 1) == 0) {
            const size_t gbase = (size_t)(kt >> 1) * N_DIM + nrow0;
#pragma unroll
            for (int t = 0; t < 4; ++t) {
                float2 f = saz2[gbase + t * 16];
                s2[t] = __float2half2_rn(f.x);
                z2[t] = __float2half2_rn(fmaf(-8.f, f.x, f.y));
            }
        }

        // prefetch next k-tile's W (in flight during MFMA)
        if (kt + 1 < kt1) {
            wbase += 1024;
#pragma unroll
            for (int f = 0; f < 8; ++f)
                qwn[f] = wbase[(f >> 2) * 512 + (f & 3) * 16];
        }

        // compute: 2 k-steps of 32; dequant b-frags in registers
#pragma unroll
        for (int s01 = 0; s01 < 2; ++s01) {
#pragma unroll
            for (int j = 0; j < 4; ++j) {
                half8 bv = dequant8(qw[s01 * 4 + j], s2[j], z2[j]);
#pragma unroll
                for (int i = 0; i < 4; ++i)
                    acc[i][j] = __builtin_amdgcn_mfma_f32_16x16x32_f16(
                        av[i * 2 + s01], bv, acc[i][j], 0, 0, 0);
            }
        }

#pragma unroll
        for (int f = 0; f < 8; ++f) qw[f] = qwn[f];
    }

    // ---------------------------------------------------------------------
    // Epilogue: C/D layout col = lane&15 (n), row = q4*4 + reg (m).
    // Cross-wave reduction: wave0 keeps rows 0..31 (i=0,1), donates i=2,3;
    // wave1 keeps rows 32..63 (i=2,3), donates i=0,1. Stride 65 pads LDS
    // banks. Each wave then stores 2048 fully-summed floats — no atomics.
    // ---------------------------------------------------------------------
    __shared__ float red[2][32 * 65];
    float* don = red[wid];
    const int id0 = wid ? 0 : 2;               // donated i-range
#pragma unroll
    for (int ii = 0; ii < 2; ++ii) {
        const int i = id0 + ii;
#pragma unroll
        for (int j = 0; j < 4; ++j)
#pragma unroll
            for (int rr = 0; rr < 4; ++rr) {
                const int rl = (i * 16 + q4 * 4 + rr) & 31;
                don[rl * 65 + j * 16 + lr] = acc[i][j][rr];
            }
    }
    __syncthreads();
    const float* oth = red[wid ^ 1];
    const int ik0 = wid ? 2 : 0;               // kept i-range
    const int n0 = nbp * 64 + lr;
#pragma unroll
    for (int ii = 0; ii < 2; ++ii) {
        const int i = ik0 + ii;
#pragma unroll
        for (int j = 0; j < 4; ++j) {
            float* o = out + (size_t)(mbp * 64 + i * 16 + q4 * 4) * N_DIM + (n0 + j * 16);
#pragma unroll
            for (int rr = 0; rr < 4; ++rr) {
                const int rl = (i * 16 + q4 * 4 + rr) & 31;
                __builtin_nontemporal_store(acc[i][j][rr] + oth[rl * 65 + j * 16 + lr],
                                            o + (size_t)rr * N_DIM);
            }
        }
    }
}

extern "C" void kernel_launch(void* const* d_in, const int* in_sizes, int n_in,
                              void* d_out, int out_size, void* d_ws, size_t ws_size,
                              hipStream_t stream) {
    const float* x   = (const float*)d_in[0];
    const int*   wq  = (const int*)d_in[1];
    const float* saz = (const float*)d_in[2];

    // ws layout: [wpk: 22,544,384 B packed weights][xb: 4 MB f16 x]
    unsigned int* wpk = (unsigned int*)d_ws;
    unsigned int* xb  = (unsigned int*)((char*)d_ws + 22544384);

    // No output memset: gemm writes every element exactly once (no atomics).
    prep_kernel<<<dim3(6528), dim3(256), 0, stream>>>(x, xb, wq, wpk);
    gemm_kernel<<<dim3(NBLK), dim3(128), 0, stream>>>(xb, wpk, saz, (float*)d_out);
}

// Round 4
// 354.239 us; speedup vs baseline: 1.1056x; 1.1056x over previous
//
#include <hip/hip_runtime.h>
#include <hip/hip_fp16.h>
#include <stdint.h>

// Problem constants: B=4, S=128 -> M=512
#define M_DIM 512
#define K_DIM 4096
#define N_DIM 11008
#define KT (K_DIM / 64)        // 64 k-tiles of BK=64
#define NB_M 8                 // 64-row strips
#define NB_N 172               // 64-col strips
#define NBLK (NB_M * NB_N)     // 1376 two-wave blocks (split-K=2 inside the block)

typedef __attribute__((ext_vector_type(8))) _Float16 half8;
typedef __attribute__((ext_vector_type(4))) float floatx4;
typedef __attribute__((ext_vector_type(4))) int intx4;
typedef __attribute__((ext_vector_type(4))) unsigned int uintx4;

__device__ __forceinline__ unsigned int h2u(__half2 h) {
    union { __half2 h; unsigned int u; } c; c.h = h; return c.u;
}
__device__ __forceinline__ __half2 u2h(unsigned int u) {
    union { unsigned int u; __half2 h; } c; c.u = u; return c.h;
}
union U4H8 { uintx4 u; half8 h; };

// one packed dword (8 codes, pair-interleaved) -> b-operand half8 (R5-proven)
__device__ __forceinline__ half8 dequant8(unsigned int dw, __half2 s2, __half2 z2) {
    const __half2 kb = u2h(0x64006400u);   // (1024, 1024)
    U4H8 r;
    unsigned int p0 = (dw & 0x000F000Fu) | 0x64006400u;
    unsigned int p1 = ((dw >> 4)  & 0x000F000Fu) | 0x64006400u;
    unsigned int p2 = ((dw >> 8)  & 0x000F000Fu) | 0x64006400u;
    unsigned int p3 = ((dw >> 12) & 0x000F000Fu) | 0x64006400u;
    r.u.x = h2u(__hfma2(__hsub2(u2h(p0), kb), s2, z2));
    r.u.y = h2u(__hfma2(__hsub2(u2h(p1), kb), s2, z2));
    r.u.z = h2u(__hfma2(__hsub2(u2h(p2), kb), s2, z2));
    r.u.w = h2u(__hfma2(__hsub2(u2h(p3), kb), s2, z2));
    return r.h;
}

// ---------------------------------------------------------------------------
// Merged prep kernel — EXACT R2 version (proven 360 us; R3's "coalesced" pack
// remap regressed 31 us by scattering each load instruction across 64 cache
// lines on the 180 MB wq stream. Old layout: 4 lanes/line loads, stores land
// as 4x contiguous 64 B segments per instruction — fine).
// Blocks [0,1024): x fp32 -> f16 fragment-linear xb. Blocks [1024,12032):
// wq int32 -> packed nibbles, tile-major [nb][kt], dword idx = q*128 + r.
// ---------------------------------------------------------------------------
__global__ __launch_bounds__(256) void prep_kernel(
        const float* __restrict__ x,  unsigned int* __restrict__ xb,
        const int*   __restrict__ wq, unsigned int* __restrict__ wpk) {
    int bx = blockIdx.x;
    if (bx < 1024) {
        int id = bx * 256 + threadIdx.x;        // chunk id, 262144 total
        int m  = id >> 9;
        int kc = id & 511;                      // k-octet within row
        const floatx4* src = (const floatx4*)(x + ((size_t)m << 12) + (kc << 3));
        floatx4 f0 = __builtin_nontemporal_load(src);
        floatx4 f1 = __builtin_nontemporal_load(src + 1);
        uintx4 v;
        v.x = h2u(__float22half2_rn(float2{f0.x, f0.y}));
        v.y = h2u(__float22half2_rn(float2{f0.z, f0.w}));
        v.z = h2u(__float22half2_rn(float2{f1.x, f1.y}));
        v.w = h2u(__float22half2_rn(float2{f1.z, f1.w}));
        int tm = m >> 7, r = m & 127, tk = kc >> 3, c = kc & 7;
        int igrp = r >> 4, rlow = r & 15, s01 = c >> 2, q = c & 3;
        int chunk = ((igrp * 2 + s01) << 6) + (q << 4) + rlow;
        size_t dstu = (((size_t)(tm * KT + tk)) << 12) + ((size_t)chunk << 2);
        *((uintx4*)(xb + dstu)) = v;
    } else {
        int id   = (bx - 1024) * 256 + threadIdx.x;
        int tile = id >> 9;                     // 5504 tiles (86 nb x 64 kt)
        int p    = id & 511;
        int nb = tile >> 6, kt = tile & 63;
        int r = p >> 2, q0 = (p & 3) * 2;
        const intx4* src = (const intx4*)(wq + (size_t)(nb * 128 + r) * K_DIM + kt * 64 + q0 * 8);
        intx4 a0 = __builtin_nontemporal_load(src);
        intx4 a1 = __builtin_nontemporal_load(src + 1);
        intx4 a2 = __builtin_nontemporal_load(src + 2);
        intx4 a3 = __builtin_nontemporal_load(src + 3);
        unsigned int u0 =
            (unsigned)a0.x | ((unsigned)a0.z << 4)  | ((unsigned)a1.x << 8)  | ((unsigned)a1.z << 12) |
            ((unsigned)a0.y << 16) | ((unsigned)a0.w << 20) | ((unsigned)a1.y << 24) | ((unsigned)a1.w << 28);
        unsigned int u1 =
            (unsigned)a2.x | ((unsigned)a2.z << 4)  | ((unsigned)a3.x << 8)  | ((unsigned)a3.z << 12) |
            ((unsigned)a2.y << 16) | ((unsigned)a2.w << 20) | ((unsigned)a3.y << 24) | ((unsigned)a3.w << 28);
        size_t base = ((size_t)tile) << 10;
        wpk[base + (q0 << 7) + r]       = u0;
        wpk[base + ((q0 + 1) << 7) + r] = u1;
    }
}

// ---------------------------------------------------------------------------
// GEMM. Two waves per block, split-K=2 inside the block (R2 structure, proven).
// NO XCD swizzle (wpk is L3-fit; swizzle measured-negative in that regime).
// NEW vs R2: FULLY SOFTWARE-PIPELINED LOADS —
//   * A split into s0/s1 halves: s1 loads issue before the s0 MFMA block
//     (~310 cyc of cover), next-kt s0 loads issue between the MFMA blocks.
//   * scales prefetched one kt ahead as raw float2 (converted VALU-only at
//     the consuming even kt).
//   * W already prefetched one kt ahead (unchanged).
// Every global load now has >=1 MFMA block (~310 cyc > ~200 cyc L2 latency)
// of independent work before its waitcnt. VGPR ~+24, still <=170 (3 w/SIMD).
// ---------------------------------------------------------------------------
__global__ __launch_bounds__(128, 3) void gemm_kernel(
        const unsigned int* __restrict__ xb,    // fragment-linear f16 x
        const unsigned int* __restrict__ wpk,   // packed nibbles, [q][r] tiles
        const float*        __restrict__ saz,   // [K/128, N, 2]
        float*              __restrict__ out)   // [M,N] fp32 (fully written here)
{
    const int bx   = blockIdx.x;
    const int mbp  = bx & 7;                   // 64-row strip 0..7
    const int nbp  = bx >> 3;                  // 64-col strip 0..171
    const int lane = threadIdx.x & 63;
    const int wid  = threadIdx.x >> 6;         // split-K half 0/1
    const int q4   = lane >> 4;
    const int lr   = lane & 15;
    const int kt0  = wid * (KT / 2);
    const int kt1  = kt0 + (KT / 2);           // 32 k-tiles per wave

    const int tm    = mbp >> 1;                // xb 128-row tile
    const int igrp0 = (mbp & 1) * 4;           // first 16-row group
    const int nbt   = nbp >> 1;                // wpk 128-col tile
    const int wn    = (nbp & 1) * 64;

    // A fragments: 16 B units; frag (i, s01) at xat[i*128 + s01*64]
    const half8* xat = (const half8*)xb
        + (((size_t)(tm * KT + kt0)) << 10) + (igrp0 << 7) + lane;

    // W: frag (j, s01) at wbase[s01*512 + j*16]; advance 1024 dwords/k-tile
    const unsigned int* wbase =
        wpk + (((size_t)(nbt * KT + kt0)) << 10) + (q4 << 7) + wn + lr;

    const float2* saz2 = (const float2*)saz;
    const int nrow0 = nbp * 64 + lr;           // n-row for frag j: +j*16
    const float2* sazp = saz2 + (size_t)(kt0 >> 1) * N_DIM + nrow0;

    floatx4 acc[4][4];
    floatx4 zero4 = {0.f, 0.f, 0.f, 0.f};
#pragma unroll
    for (int i = 0; i < 4; ++i)
#pragma unroll
        for (int j = 0; j < 4; ++j)
            acc[i][j] = zero4;

    // prologue: W dwords + A s0-half + raw scales for first group
    unsigned int qw[8], qwn[8];
#pragma unroll
    for (int f = 0; f < 8; ++f)
        qw[f] = wbase[(f >> 2) * 512 + (f & 3) * 16];

    half8 av0[4], av1[4], av0n[4];
#pragma unroll
    for (int i = 0; i < 4; ++i)
        av0[i] = xat[i * 128];

    float2 sf[4];
#pragma unroll
    for (int t = 0; t < 4; ++t)
        sf[t] = sazp[t * 16];

    __half2 s2[4], z2[4];

    for (int kt = kt0; kt < kt1; ++kt) {
        const bool more = (kt + 1 < kt1);

        // convert prefetched scales (VALU-only; sf loaded >=1 kt ago)
        if ((kt & 1) == 0) {
#pragma unroll
            for (int t = 0; t < 4; ++t) {
                s2[t] = __float2half2_rn(sf[t].x);
                z2[t] = __float2half2_rn(fmaf(-8.f, sf[t].x, sf[t].y));
            }
        } else if (more) {
            // issue raw-scale loads for the next group during the odd kt
            sazp += N_DIM;
#pragma unroll
            for (int t = 0; t < 4; ++t)
                sf[t] = sazp[t * 16];
        }

        // issue next-kt W prefetch
        if (more) {
            wbase += 1024;
#pragma unroll
            for (int f = 0; f < 8; ++f)
                qwn[f] = wbase[(f >> 2) * 512 + (f & 3) * 16];
        }

        // issue this-kt s1-half A loads (consumed after the s0 MFMA block)
#pragma unroll
        for (int i = 0; i < 4; ++i)
            av1[i] = xat[i * 128 + 64];

        // s01 = 0: dequant + 16 MFMA on av0 (prefetched during prev iter)
#pragma unroll
        for (int j = 0; j < 4; ++j) {
            half8 bv = dequant8(qw[j], s2[j], z2[j]);
#pragma unroll
            for (int i = 0; i < 4; ++i)
                acc[i][j] = __builtin_amdgcn_mfma_f32_16x16x32_f16(
                    av0[i], bv, acc[i][j], 0, 0, 0);
        }

        // issue next-kt s0-half A loads (consumed next iteration)
        if (more) {
#pragma unroll
            for (int i = 0; i < 4; ++i)
                av0n[i] = xat[1024 + i * 128];
        }

        // s01 = 1: dequant + 16 MFMA on av1 (covered by the s0 block)
#pragma unroll
        for (int j = 0; j < 4; ++j) {
            half8 bv = dequant8(qw[4 + j], s2[j], z2[j]);
#pragma unroll
            for (int i = 0; i < 4; ++i)
                acc[i][j] = __builtin_amdgcn_mfma_f32_16x16x32_f16(
                    av1[i], bv, acc[i][j], 0, 0, 0);
        }

        xat += 1024;
#pragma unroll
        for (int i = 0; i < 4; ++i) av0[i] = av0n[i];
#pragma unroll
        for (int f = 0; f < 8; ++f) qw[f] = qwn[f];
    }

    // ---------------------------------------------------------------------
    // Epilogue: C/D layout col = lane&15 (n), row = q4*4 + reg (m).
    // Cross-wave reduction through padded LDS; plain nontemporal stores,
    // no atomics (proven R2).
    // ---------------------------------------------------------------------
    __shared__ float red[2][32 * 65];
    float* don = red[wid];
    const int id0 = wid ? 0 : 2;               // donated i-range
#pragma unroll
    for (int ii = 0; ii < 2; ++ii) {
        const int i = id0 + ii;
#pragma unroll
        for (int j = 0; j < 4; ++j)
#pragma unroll
            for (int rr = 0; rr < 4; ++rr) {
                const int rl = (i * 16 + q4 * 4 + rr) & 31;
                don[rl * 65 + j * 16 + lr] = acc[i][j][rr];
            }
    }
    __syncthreads();
    const float* oth = red[wid ^ 1];
    const int ik0 = wid ? 2 : 0;               // kept i-range
    const int n0 = nbp * 64 + lr;
#pragma unroll
    for (int ii = 0; ii < 2; ++ii) {
        const int i = ik0 + ii;
#pragma unroll
        for (int j = 0; j < 4; ++j) {
            float* o = out + (size_t)(mbp * 64 + i * 16 + q4 * 4) * N_DIM + (n0 + j * 16);
#pragma unroll
            for (int rr = 0; rr < 4; ++rr) {
                const int rl = (i * 16 + q4 * 4 + rr) & 31;
                __builtin_nontemporal_store(acc[i][j][rr] + oth[rl * 65 + j * 16 + lr],
                                            o + (size_t)rr * N_DIM);
            }
        }
    }
}

extern "C" void kernel_launch(void* const* d_in, const int* in_sizes, int n_in,
                              void* d_out, int out_size, void* d_ws, size_t ws_size,
                              hipStream_t stream) {
    const float* x   = (const float*)d_in[0];
    const int*   wq  = (const int*)d_in[1];
    const float* saz = (const float*)d_in[2];

    // ws layout: [wpk: 22,544,384 B packed weights][xb: 4 MB f16 x]
    unsigned int* wpk = (unsigned int*)d_ws;
    unsigned int* xb  = (unsigned int*)((char*)d_ws + 22544384);

    // No output memset: gemm writes every element exactly once (no atomics).
    prep_kernel<<<dim3(12032), dim3(256), 0, stream>>>(x, xb, wq, wpk);
    gemm_kernel<<<dim3(NBLK), dim3(128), 0, stream>>>(xb, wpk, saz, (float*)d_out);
}